// Round 18
// baseline (651.112 us; speedup 1.0000x reference)
//
#include <hip/hip_runtime.h>
#include <math.h>

#define TOK 9232      // B*N = 16*577
#define EMB 1024
#define NQKV 3072
#define FFD 4096
#define FF2 4352      // 4096 + 256 adapter cols
#define NSEQ 577

typedef __bf16 bf16x8 __attribute__((ext_vector_type(8)));
typedef float f32x4 __attribute__((ext_vector_type(4)));
typedef unsigned short ushort8 __attribute__((ext_vector_type(8)));
typedef unsigned short ushort4v __attribute__((ext_vector_type(4)));

typedef __attribute__((address_space(3))) unsigned int lds_u32_t;
typedef const __attribute__((address_space(1))) unsigned int glob_u32_t;

__device__ __forceinline__ void async16(void* lds, const void* g) {
    __builtin_amdgcn_global_load_lds((glob_u32_t*)g, (lds_u32_t*)lds, 16, 0, 0);
}

__device__ __forceinline__ unsigned short f2bf(float f) {
    unsigned int u = __builtin_bit_cast(unsigned int, f);
    u = (u + 0x7fffu + ((u >> 16) & 1u)) >> 16;
    return (unsigned short)u;
}
__device__ __forceinline__ float bf2f(unsigned short s) {
    unsigned int u = ((unsigned int)s) << 16;
    return __builtin_bit_cast(float, u);
}
__device__ __forceinline__ float gelu_exact(float x) {
    return 0.5f * x * (1.0f + erff(x * 0.70710678118654752f));
}

// ---------- merged weight conversion (5 contiguous f32->bf16 segments) ----------
__global__ void k_pack_all(const float* __restrict__ s_qkv, const float* __restrict__ s_proj,
                           const float* __restrict__ s_fc1, const float* __restrict__ s_la,
                           const float* __restrict__ s_ad,
                           unsigned short* __restrict__ d_qkv, unsigned short* __restrict__ d_proj,
                           unsigned short* __restrict__ d_fc1, unsigned short* __restrict__ d_la,
                           unsigned short* __restrict__ d_ad) {
    int stride = gridDim.x * 256;
    for (int i4 = blockIdx.x * 256 + threadIdx.x; i4 < 2179072; i4 += stride) {
        const float* s; unsigned short* d; int local;
        if (i4 < 786432)       { s = s_qkv;  d = d_qkv;  local = i4; }
        else if (i4 < 1048576) { s = s_proj; d = d_proj; local = i4 - 786432; }
        else if (i4 < 2097152) { s = s_fc1;  d = d_fc1;  local = i4 - 1048576; }
        else if (i4 < 2113536) { s = s_la;   d = d_la;   local = i4 - 2097152; }
        else                   { s = s_ad;   d = d_ad;   local = i4 - 2113536; }
        float4 v = ((const float4*)s)[local];
        ushort4v o;
        o[0] = f2bf(v.x); o[1] = f2bf(v.y); o[2] = f2bf(v.z); o[3] = f2bf(v.w);
        ((ushort4v*)d)[local] = o;
    }
}
// fc2_w [1024][4096] -> w_fc2cat[o][0..4096), ldw 4352
__global__ void k_pack_fc2cat(const float* __restrict__ src, unsigned short* __restrict__ dst) {
    int i = blockIdx.x * 256 + threadIdx.x;
    if (i >= 1024 * 1024) return;          // float4 units
    int o = i >> 10, c4 = i & 1023;
    float4 v = ((const float4*)src)[i];
    ushort4v q;
    q[0] = f2bf(v.x); q[1] = f2bf(v.y); q[2] = f2bf(v.z); q[3] = f2bf(v.w);
    *(ushort4v*)(dst + (size_t)o * FF2 + c4 * 4) = q;
}
// ad_up_w [4][1024][64] -> w_fc2cat[o][4096 + x*64+h]
__global__ void k_pack_u(const float* __restrict__ Uw, unsigned short* __restrict__ out) {
    int i = blockIdx.x * 256 + threadIdx.x;
    if (i >= 1024 * 256) return;
    int o = i >> 8, j = i & 255, x = j >> 6, h = j & 63;
    out[(size_t)o * FF2 + 4096 + j] = f2bf(Uw[x * 65536 + o * 64 + h]);
}
// lora_B [4][3072][16] -> Bcat[o][x*16+r]
__global__ void k_pack_bcat(const float* __restrict__ Bw, unsigned short* __restrict__ out) {
    int i = blockIdx.x * 256 + threadIdx.x;
    if (i >= 3072 * 64) return;
    int o = i >> 6, j = i & 63, x = j >> 4, r = j & 15;
    out[o * 64 + j] = f2bf(Bw[x * 3072 * 16 + o * 16 + r]);
}
// fc1 bias concat: [0,4096) = fc1_b, [4096,4352) = ad_down_b flat
__global__ void k_pack_bias(const float* __restrict__ b1, const float* __restrict__ b2,
                            float* __restrict__ out) {
    int i = blockIdx.x * 256 + threadIdx.x;
    if (i >= FF2) return;
    out[i] = (i < 4096) ? b1[i] : b2[i - 4096];
}

// ---------- fused layernorm + 4-expert gate softmax (+ optional d_out prefill) ----------
template<bool FC2I>
__global__ __launch_bounds__(256) void k_ln_gates(const float* __restrict__ x,
                                                  const float* __restrict__ g,
                                                  const float* __restrict__ b,
                                                  const float* __restrict__ gw,
                                                  unsigned short* __restrict__ out,
                                                  float* __restrict__ gates,
                                                  const float* __restrict__ fc2b,
                                                  const float* __restrict__ upb,
                                                  float* __restrict__ out2) {
    int t = blockIdx.x;
    int tid = threadIdx.x;
    const float* xp = x + (size_t)t * EMB;
    float4 v = ((const float4*)xp)[tid];
    float s = v.x + v.y + v.z + v.w;
    float sq = v.x * v.x + v.y * v.y + v.z * v.z + v.w * v.w;
    #pragma unroll
    for (int off = 32; off > 0; off >>= 1) {
        s += __shfl_down(s, off);
        sq += __shfl_down(sq, off);
    }
    __shared__ float red[8];
    if ((tid & 63) == 0) { red[tid >> 6] = s; red[(tid >> 6) + 4] = sq; }
    __syncthreads();
    float S = red[0] + red[1] + red[2] + red[3];
    float SQ = red[4] + red[5] + red[6] + red[7];
    float mean = S * (1.0f / EMB);
    float var = SQ * (1.0f / EMB) - mean * mean;
    float rstd = rsqrtf(var + 1e-6f);
    float4 gv = ((const float4*)g)[tid];
    float4 bv = ((const float4*)b)[tid];
    float n0 = (v.x - mean) * rstd * gv.x + bv.x;
    float n1 = (v.y - mean) * rstd * gv.y + bv.y;
    float n2 = (v.z - mean) * rstd * gv.z + bv.z;
    float n3 = (v.w - mean) * rstd * gv.w + bv.w;
    ushort4v o;
    o[0] = f2bf(n0); o[1] = f2bf(n1); o[2] = f2bf(n2); o[3] = f2bf(n3);
    ((ushort4v*)(out + (size_t)t * EMB))[tid] = o;
    float p[4];
    #pragma unroll
    for (int xx = 0; xx < 4; ++xx) {
        float4 gr = ((const float4*)(gw + xx * EMB))[tid];
        p[xx] = n0 * gr.x + n1 * gr.y + n2 * gr.z + n3 * gr.w;
    }
    #pragma unroll
    for (int off = 32; off > 0; off >>= 1) {
        #pragma unroll
        for (int xx = 0; xx < 4; ++xx) p[xx] += __shfl_down(p[xx], off);
    }
    __shared__ float red2[4][4];
    __shared__ float agb[4];
    if ((tid & 63) == 0) {
        #pragma unroll
        for (int xx = 0; xx < 4; ++xx) red2[tid >> 6][xx] = p[xx];
    }
    __syncthreads();
    if (tid == 0) {
        float l[4];
        #pragma unroll
        for (int xx = 0; xx < 4; ++xx) l[xx] = red2[0][xx] + red2[1][xx] + red2[2][xx] + red2[3][xx];
        float m = fmaxf(fmaxf(l[0], l[1]), fmaxf(l[2], l[3]));
        float e[4], ssum = 0.f;
        #pragma unroll
        for (int xx = 0; xx < 4; ++xx) { e[xx] = expf(l[xx] - m); ssum += e[xx]; }
        float inv = 1.0f / ssum;
        #pragma unroll
        for (int xx = 0; xx < 4; ++xx) {
            float gg = e[xx] * inv;
            gates[t * 4 + xx] = gg;
            if (FC2I) agb[xx] = gg;
        }
    }
    if (FC2I) {
        __syncthreads();
        float g0 = agb[0], g1 = agb[1], g2 = agb[2], g3 = agb[3];
        float4 b0 = ((const float4*)(upb + 0 * EMB))[tid];
        float4 b1 = ((const float4*)(upb + 1 * EMB))[tid];
        float4 b2 = ((const float4*)(upb + 2 * EMB))[tid];
        float4 b3 = ((const float4*)(upb + 3 * EMB))[tid];
        float4 fb = ((const float4*)fc2b)[tid];
        float4 r;
        r.x = v.x + fb.x + g0 * b0.x + g1 * b1.x + g2 * b2.x + g3 * b3.x;
        r.y = v.y + fb.y + g0 * b0.y + g1 * b1.y + g2 * b2.y + g3 * b3.y;
        r.z = v.z + fb.z + g0 * b0.z + g1 * b1.z + g2 * b2.z + g3 * b3.z;
        r.w = v.w + fb.w + g0 * b0.w + g1 * b1.w + g2 * b2.w + g3 * b3.w;
        ((float4*)(out2 + (size_t)t * EMB))[tid] = r;
    }
}

// ---------- MFMA GEMM (R15 structure; hazards proven R11; swizzle 0-conflict R12) ----------
// NSPLIT: W rows >= NSPLIT come from W2 (rebased), enabling column-concatenated weights
// (fc1 | adapter-down). Tiles never straddle NSPLIT (NSPLIT % 64 == 0).
// AD: epilogue cols >= 4096 multiplied by aux gate (group 64).
#define BAR __builtin_amdgcn_s_barrier()

template<bool GELU, bool BF16OUT, int GG, bool AD, int NSPLIT, int MF, int NF, int CN>
__global__ __launch_bounds__(256) void k_gemm(
    const unsigned short* __restrict__ A, int lda,
    const unsigned short* __restrict__ W, int ldw, int K1,
    int M, int N,
    const unsigned short* __restrict__ A2, const unsigned short* __restrict__ W2, int K2,
    const float* __restrict__ bias, const float* __restrict__ resid,
    const float* __restrict__ aux,
    void* __restrict__ Cout, int ldc, int gy)
{
    constexpr int CA = MF * 4;            // A chunks (8 rows x 64 cols = 1KB each)
    constexpr int CB = NF * 4;            // B chunks
    constexpr int CT = CA + CB;
    constexpr int CPW = CT / 4;           // chunks staged per wave
    constexpr int BUFB = CT * 1024;
    __shared__ __attribute__((aligned(16))) char Sbuf[2 * BUFB];

    int tid = threadIdx.x;
    int nwg = gridDim.x, orig = blockIdx.x;
    int xcd = orig & 7, lid = orig >> 3;
    int q = nwg >> 3, r = nwg & 7;
    int wg = (xcd < r ? xcd * (q + 1) : r * (q + 1) + (xcd - r) * q) + lid;
    // chunked decode: (nc, mt, ni)
    int nmt = nwg / gy;
    int ni = wg % CN;
    int tmp = wg / CN;
    int mt = tmp % nmt;
    int nt = (tmp / nmt) * CN + ni;
    int bm = mt * (MF * 32);
    int bn = nt * (NF * 32);

    int l = tid & 63, w = tid >> 6;
    int wr = w >> 1, wc = w & 1;
    int lr = l & 15;
    int sslot = (((l & 7) ^ (l >> 3)) << 3);   // inverse-swizzled source slot (elems)

    int KT1 = K1 >> 6, KT2 = K2 >> 6;
    int KT = KT1 + KT2;

    const unsigned short* A2s = A2 ? A2 : A;
    int K2s = A2 ? K2 : lda;

    // per-thread staging sources (rows clamped: garbage feeds only dead rows/cols)
    const unsigned short* sp1[CPW];
    const unsigned short* sp2[CPW];
    int ldsu[CPW];                        // wave-uniform LDS chunk base offsets
    #pragma unroll
    for (int j = 0; j < CPW; ++j) {
        int c = w * CPW + j;
        ldsu[j] = c << 10;
        if (c < CA) {
            int rw = bm + c * 8 + (l >> 3); if (rw > M - 1) rw = M - 1;
            sp1[j] = A + (size_t)rw * lda + sslot;
            sp2[j] = A2s + (size_t)rw * K2s + sslot;
        } else {
            int rw = bn + (c - CA) * 8 + (l >> 3); if (rw > N - 1) rw = N - 1;
            const unsigned short* wp;
            if (NSPLIT > 0 && rw >= NSPLIT) wp = W2 + (size_t)(rw - NSPLIT) * ldw + sslot;
            else                            wp = W + (size_t)rw * ldw + sslot;
            sp1[j] = wp;
            sp2[j] = (NSPLIT > 0) ? wp
                     : ((A2 ? W2 : W) + (size_t)rw * K2s + sslot);
        }
    }

    // swizzled, loop-invariant ds_read byte offsets
    int offA[MF][2], offB[NF][2];
    #pragma unroll
    for (int m = 0; m < MF; ++m)
        #pragma unroll
        for (int ks = 0; ks < 2; ++ks) {
            int rw = wr * (MF * 16) + m * 16 + lr;
            int g = ks * 4 + (l >> 4);
            offA[m][ks] = (rw << 7) + ((g ^ (rw & 7)) << 4);
        }
    #pragma unroll
    for (int n = 0; n < NF; ++n)
        #pragma unroll
        for (int ks = 0; ks < 2; ++ks) {
            int rw = wc * (NF * 16) + n * 16 + lr;
            int g = ks * 4 + (l >> 4);
            offB[n][ks] = (CA << 10) + (rw << 7) + ((g ^ (rw & 7)) << 4);
        }

    f32x4 acc[MF][NF];
    #pragma unroll
    for (int m = 0; m < MF; ++m)
        #pragma unroll
        for (int n = 0; n < NF; ++n) acc[m][n] = (f32x4){0.f, 0.f, 0.f, 0.f};

    auto stage = [&](int ss, int bb) {
        char* db = Sbuf + bb * BUFB;
        if (ss < KT1) {
            int ko = ss << 6;
            #pragma unroll
            for (int j = 0; j < CPW; ++j) async16(db + ldsu[j], sp1[j] + ko);
        } else {
            int ko = (ss - KT1) << 6;
            #pragma unroll
            for (int j = 0; j < CPW; ++j) async16(db + ldsu[j], sp2[j] + ko);
        }
    };

    stage(0, 0);

    #pragma unroll 1
    for (int t = 0; t < KT; ++t) {
        asm volatile("s_waitcnt vmcnt(0)" ::: "memory");  // my stage(t) landed
        BAR;                                // all waves' stage(t) landed; t-1 reads consumed
        __builtin_amdgcn_sched_barrier(0);  // pin reads below the barrier
        int s = t + 1; if (s >= KT) s = 0;  // wrap re-stage: buffer never read after
        stage(s, (t + 1) & 1);              // WAR safe post-barrier (buf read at t-1)
        const char* base = Sbuf + (t & 1) * BUFB;
        bf16x8 af[MF][2], bfr[NF][2];
        #pragma unroll
        for (int m = 0; m < MF; ++m)
            #pragma unroll
            for (int ks = 0; ks < 2; ++ks) af[m][ks] = *(const bf16x8*)(base + offA[m][ks]);
        #pragma unroll
        for (int n = 0; n < NF; ++n)
            #pragma unroll
            for (int ks = 0; ks < 2; ++ks) bfr[n][ks] = *(const bf16x8*)(base + offB[n][ks]);
        __builtin_amdgcn_s_setprio(1);
        #pragma unroll
        for (int m = 0; m < MF; ++m)
            #pragma unroll
            for (int n = 0; n < NF; ++n)
                #pragma unroll
                for (int ks = 0; ks < 2; ++ks)
                    acc[m][n] = __builtin_amdgcn_mfma_f32_16x16x32_bf16(af[m][ks], bfr[n][ks], acc[m][n], 0, 0, 0);
        __builtin_amdgcn_s_setprio(0);
    }

    int rbase = bm + wr * (MF * 16);
    int cbase = bn + wc * (NF * 16);
    #pragma unroll
    for (int n = 0; n < NF; ++n) {
        int col = cbase + n * 16 + lr;
        if (col >= N) continue;
        float bv = bias ? bias[col] : 0.0f;
        #pragma unroll
        for (int m = 0; m < MF; ++m) {
            #pragma unroll
            for (int rr = 0; rr < 4; ++rr) {
                int row = rbase + m * 16 + (l >> 4) * 4 + rr;
                if (row >= M) continue;
                float c = acc[m][n][rr] + bv;
                if (GELU) c = gelu_exact(c);
                if (GG > 0) c *= aux[row * 4 + col / (GG > 0 ? GG : 1)];
                if (AD) { if (col >= 4096) c *= aux[row * 4 + ((col - 4096) >> 6)]; }
                if (resid) c += resid[(size_t)row * ldc + col];
                if (BF16OUT) ((unsigned short*)Cout)[(size_t)row * ldc + col] = f2bf(c);
                else ((float*)Cout)[(size_t)row * ldc + col] = c;
            }
        }
    }
}

// ---------- flash attention: one block per (b*h, 64-row q tile) ----------
__global__ __launch_bounds__(256) void k_attn(const unsigned short* __restrict__ qkv,
                                              unsigned short* __restrict__ ctx) {
    int bh = blockIdx.x;
    int qt = blockIdx.y;
    int b = bh >> 4, h = bh & 15;
    int tid = threadIdx.x;
    int l = tid & 63;
    int w = tid >> 6;
    int lr = l & 15;
    int lk = (l >> 4) * 8;

    __shared__ unsigned short Qs[64][72];
    __shared__ unsigned short Ks[64][72];
    __shared__ unsigned short Vt[64][72];
    __shared__ unsigned short Ps[64][72];

    const size_t base = (size_t)b * NSEQ * NQKV + (size_t)h * 64;
    int q0 = qt * 64;

    {   // vector Q staging; 1/8 scale folded into S post-MFMA
        int row = tid >> 2, ds = (tid & 3) * 16;
        int qrow = q0 + row;
        if (qrow < NSEQ) {
            const unsigned short* src = qkv + base + (size_t)qrow * NQKV + ds;
            *(ushort8*)&Qs[row][ds] = *(const ushort8*)src;
            *(ushort8*)&Qs[row][ds + 8] = *(const ushort8*)(src + 8);
        } else {
            ushort8 z = {};
            *(ushort8*)&Qs[row][ds] = z;
            *(ushort8*)&Qs[row][ds + 8] = z;
        }
    }

    float m_run[4], l_run[4];
    f32x4 o[4];
    #pragma unroll
    for (int r = 0; r < 4; ++r) { m_run[r] = -1e30f; l_run[r] = 0.0f; }
    #pragma unroll
    for (int n = 0; n < 4; ++n) o[n] = (f32x4){0.f, 0.f, 0.f, 0.f};

    for (int kt = 0; kt < 10; ++kt) {
        __syncthreads();
        {
            int row = tid >> 2, ds = (tid & 3) * 16;
            int key = kt * 64 + row;
            if (key < NSEQ) {
                const unsigned short* ksrc = qkv + base + (size_t)key * NQKV + 1024 + ds;
                *(ushort8*)&Ks[row][ds] = *(const ushort8*)ksrc;
                *(ushort8*)&Ks[row][ds + 8] = *(const ushort8*)(ksrc + 8);
                const unsigned short* vsrc = qkv + base + (size_t)key * NQKV + 2048 + ds;
                #pragma unroll
                for (int j = 0; j < 16; ++j) Vt[ds + j][row] = vsrc[j];
            } else {
                ushort8 z = {};
                *(ushort8*)&Ks[row][ds] = z;
                *(ushort8*)&Ks[row][ds + 8] = z;
                #pragma unroll
                for (int j = 0; j < 16; ++j) Vt[ds + j][row] = 0;
            }
        }
        __syncthreads();

        f32x4 s[4];
        #pragma unroll
        for (int n = 0; n < 4; ++n) s[n] = (f32x4){0.f, 0.f, 0.f, 0.f};
        #pragma unroll
        for (int ks = 0; ks < 2; ++ks) {
            bf16x8 qa = *(const bf16x8*)&Qs[w * 16 + lr][ks * 32 + lk];
            #pragma unroll
            for (int n = 0; n < 4; ++n) {
                bf16x8 kb = *(const bf16x8*)&Ks[n * 16 + lr][ks * 32 + lk];
                s[n] = __builtin_amdgcn_mfma_f32_16x16x32_bf16(qa, kb, s[n], 0, 0, 0);
            }
        }
        #pragma unroll
        for (int n = 0; n < 4; ++n) {
            #pragma unroll
            for (int r = 0; r < 4; ++r) s[n][r] *= 0.125f;
        }
        #pragma unroll
        for (int n = 0; n < 4; ++n) {
            int col = kt * 64 + n * 16 + lr;
            if (col >= NSEQ) {
                #pragma unroll
                for (int r = 0; r < 4; ++r) s[n][r] = -1e30f;
            }
        }
        float tmax[4];
        #pragma unroll
        for (int r = 0; r < 4; ++r)
            tmax[r] = fmaxf(fmaxf(s[0][r], s[1][r]), fmaxf(s[2][r], s[3][r]));
        #pragma unroll
        for (int off = 1; off < 16; off <<= 1) {
            #pragma unroll
            for (int r = 0; r < 4; ++r) tmax[r] = fmaxf(tmax[r], __shfl_xor(tmax[r], off));
        }
        float alpha[4], rs[4];
        #pragma unroll
        for (int r = 0; r < 4; ++r) {
            float mn = fmaxf(m_run[r], tmax[r]);
            alpha[r] = __expf(m_run[r] - mn);
            m_run[r] = mn;
            rs[r] = 0.0f;
        }
        #pragma unroll
        for (int n = 0; n < 4; ++n) {
            #pragma unroll
            for (int r = 0; r < 4; ++r) {
                float p = __expf(s[n][r] - m_run[r]);
                s[n][r] = p;
                rs[r] += p;
            }
        }
        #pragma unroll
        for (int off = 1; off < 16; off <<= 1) {
            #pragma unroll
            for (int r = 0; r < 4; ++r) rs[r] += __shfl_xor(rs[r], off);
        }
        #pragma unroll
        for (int r = 0; r < 4; ++r) l_run[r] = l_run[r] * alpha[r] + rs[r];
        #pragma unroll
        for (int n = 0; n < 4; ++n) {
            #pragma unroll
            for (int r = 0; r < 4; ++r) o[n][r] *= alpha[r];
        }
        #pragma unroll
        for (int n = 0; n < 4; ++n) {
            #pragma unroll
            for (int r = 0; r < 4; ++r)
                Ps[w * 16 + (l >> 4) * 4 + r][n * 16 + lr] = f2bf(s[n][r]);
        }
        __syncthreads();
        #pragma unroll
        for (int ks = 0; ks < 2; ++ks) {
            bf16x8 pa = *(const bf16x8*)&Ps[w * 16 + lr][ks * 32 + lk];
            #pragma unroll
            for (int n = 0; n < 4; ++n) {
                bf16x8 vb = *(const bf16x8*)&Vt[n * 16 + lr][ks * 32 + lk];
                o[n] = __builtin_amdgcn_mfma_f32_16x16x32_bf16(pa, vb, o[n], 0, 0, 0);
            }
        }
    }
    #pragma unroll
    for (int r = 0; r < 4; ++r) {
        int qrow = q0 + w * 16 + (l >> 4) * 4 + r;
        if (qrow < NSEQ) {
            float inv = (l_run[r] > 0.f) ? 1.0f / l_run[r] : 0.0f;
            #pragma unroll
            for (int n = 0; n < 4; ++n)
                ctx[((size_t)b * NSEQ + qrow) * EMB + h * 64 + n * 16 + lr] = f2bf(o[n][r] * inv);
        }
    }
}

extern "C" void kernel_launch(void* const* d_in, const int* in_sizes, int n_in,
                              void* d_out, int out_size, void* d_ws, size_t ws_size,
                              hipStream_t stream) {
    const float* tokens      = (const float*)d_in[0];
    const float* ln1_g       = (const float*)d_in[1];
    const float* ln1_b       = (const float*)d_in[2];
    const float* qkv_w       = (const float*)d_in[3];
    const float* qkv_b       = (const float*)d_in[4];
    const float* proj_w      = (const float*)d_in[5];
    const float* proj_b      = (const float*)d_in[6];
    const float* lora_gate_w = (const float*)d_in[7];
    const float* lora_A      = (const float*)d_in[8];
    const float* lora_B      = (const float*)d_in[9];
    const float* ln2_g       = (const float*)d_in[10];
    const float* ln2_b       = (const float*)d_in[11];
    const float* fc1_w       = (const float*)d_in[12];
    const float* fc1_b       = (const float*)d_in[13];
    const float* fc2_w       = (const float*)d_in[14];
    const float* fc2_b       = (const float*)d_in[15];
    const float* ad_gate_w   = (const float*)d_in[16];
    const float* ad_down_w   = (const float*)d_in[17];
    const float* ad_down_b   = (const float*)d_in[18];
    const float* ad_up_w     = (const float*)d_in[19];
    const float* ad_up_b     = (const float*)d_in[20];

    char* ws = (char*)d_ws;
    size_t off = 0;
    auto alloc = [&](size_t bytes) -> void* {
        void* p = ws + off;
        off += (bytes + 255) & ~(size_t)255;
        return p;
    };

    unsigned short* w_qkv    = (unsigned short*)alloc((size_t)NQKV * EMB * 2);
    unsigned short* w_proj   = (unsigned short*)alloc((size_t)EMB * EMB * 2);
    unsigned short* w_fc1    = (unsigned short*)alloc((size_t)FFD * EMB * 2);
    unsigned short* w_fc2cat = (unsigned short*)alloc((size_t)EMB * FF2 * 2);
    unsigned short* w_acat   = (unsigned short*)alloc((size_t)64 * EMB * 2);
    unsigned short* w_bcat   = (unsigned short*)alloc((size_t)NQKV * 64 * 2);
    unsigned short* w_dcat   = (unsigned short*)alloc((size_t)256 * EMB * 2);
    float* b_fc1cat = (float*)alloc((size_t)FF2 * 4);

    unsigned short* u1 = (unsigned short*)alloc((size_t)TOK * EMB * 2);  // normed -> mlpin
    unsigned short* u2 = (unsigned short*)alloc((size_t)TOK * EMB * 2);  // ctx
    unsigned short* u3 = (unsigned short*)alloc((size_t)TOK * FF2 * 2);  // qkv -> h1cat
    float* tok2  = (float*)alloc((size_t)TOK * EMB * 4);
    unsigned short* hw  = (unsigned short*)alloc((size_t)TOK * 64 * 2);
    float* gates = (float*)alloc((size_t)TOK * 4 * 4);
    float* ag    = (float*)alloc((size_t)TOK * 4 * 4);

    unsigned short* normed = u1;
    unsigned short* mlpin  = u1;
    unsigned short* ctx    = u2;
    unsigned short* qkv    = u3;
    unsigned short* h1cat  = u3;     // [TOK][4352]

    // ---- weight conversion / packing ----
    k_pack_all<<<2048, 256, 0, stream>>>(qkv_w, proj_w, fc1_w, lora_A, ad_down_w,
                                         w_qkv, w_proj, w_fc1, w_acat, w_dcat);
    k_pack_fc2cat<<<(1024 * 1024 + 255) / 256, 256, 0, stream>>>(fc2_w, w_fc2cat);
    k_pack_u<<<(EMB * 256 + 255) / 256, 256, 0, stream>>>(ad_up_w, w_fc2cat);
    k_pack_bcat<<<(NQKV * 64 + 255) / 256, 256, 0, stream>>>(lora_B, w_bcat);
    k_pack_bias<<<(FF2 + 255) / 256, 256, 0, stream>>>(fc1_b, ad_down_b, b_fc1cat);

    // ---- forward ----
    k_ln_gates<false><<<TOK, 256, 0, stream>>>(tokens, ln1_g, ln1_b, lora_gate_w,
                                               normed, gates, nullptr, nullptr, nullptr);
    k_gemm<false, true, 16, false, 0, 2, 2, 1><<<145, 256, 0, stream>>>(
        normed, EMB, w_acat, EMB, EMB, TOK, 64,
        nullptr, nullptr, 0, nullptr, nullptr, gates, hw, 64, 1);
    k_gemm<false, true, 0, false, 0, 4, 2, 8><<<73 * 48, 256, 0, stream>>>(
        normed, EMB, w_qkv, EMB, EMB, TOK, NQKV,
        hw, w_bcat, 64, qkv_b, nullptr, nullptr, qkv, NQKV, 48);
    k_attn<<<dim3(256, 10), 256, 0, stream>>>(qkv, ctx);
    k_gemm<false, false, 0, false, 0, 4, 2, 8><<<73 * 16, 256, 0, stream>>>(
        ctx, EMB, w_proj, EMB, EMB, TOK, EMB,
        nullptr, nullptr, 0, proj_b, tokens, nullptr, tok2, EMB, 16);
    k_ln_gates<true><<<TOK, 256, 0, stream>>>(tok2, ln2_g, ln2_b, ad_gate_w,
                                              mlpin, ag, fc2_b, ad_up_b, (float*)d_out);
    // h1cat = [gelu(mlpin@fc1^T+b) | ag*gelu(mlpin@ad_down^T+db)]  (W2=w_dcat for rows>=4096)
    k_gemm<true, true, 0, true, 4096, 4, 2, 4><<<73 * 68, 256, 0, stream>>>(
        mlpin, EMB, w_fc1, EMB, EMB, TOK, FF2,
        nullptr, w_dcat, 0, b_fc1cat, nullptr, ag, h1cat, FF2, 68);
    // d_out = prefill + h1cat @ w_fc2cat^T  (single source K=4352)
    k_gemm<false, false, 0, false, 0, 4, 2, 8><<<73 * 16, 256, 0, stream>>>(
        h1cat, FF2, w_fc2cat, FF2, FF2, TOK, EMB,
        nullptr, nullptr, 0, nullptr, (const float*)d_out, nullptr, (float*)d_out, EMB, 16);
}

// Round 19
// 632.647 us; speedup vs baseline: 1.0292x; 1.0292x over previous
//
#include <hip/hip_runtime.h>
#include <math.h>

#define TOK 9232      // B*N = 16*577
#define EMB 1024
#define NQKV 3072
#define FFD 4096
#define NSEQ 577

typedef __bf16 bf16x8 __attribute__((ext_vector_type(8)));
typedef float f32x4 __attribute__((ext_vector_type(4)));
typedef unsigned short ushort8 __attribute__((ext_vector_type(8)));
typedef unsigned short ushort4v __attribute__((ext_vector_type(4)));

typedef __attribute__((address_space(3))) unsigned int lds_u32_t;
typedef const __attribute__((address_space(1))) unsigned int glob_u32_t;

__device__ __forceinline__ void async16(void* lds, const void* g) {
    __builtin_amdgcn_global_load_lds((glob_u32_t*)g, (lds_u32_t*)lds, 16, 0, 0);
}

__device__ __forceinline__ unsigned short f2bf(float f) {
    unsigned int u = __builtin_bit_cast(unsigned int, f);
    u = (u + 0x7fffu + ((u >> 16) & 1u)) >> 16;
    return (unsigned short)u;
}
__device__ __forceinline__ float bf2f(unsigned short s) {
    unsigned int u = ((unsigned int)s) << 16;
    return __builtin_bit_cast(float, u);
}
__device__ __forceinline__ float gelu_exact(float x) {
    return 0.5f * x * (1.0f + erff(x * 0.70710678118654752f));
}

// ---------- merged weight conversion (6 contiguous f32->bf16 segments) ----------
__global__ void k_pack_all(const float* __restrict__ s_qkv, const float* __restrict__ s_proj,
                           const float* __restrict__ s_fc1, const float* __restrict__ s_fc2,
                           const float* __restrict__ s_la,  const float* __restrict__ s_ad,
                           unsigned short* __restrict__ d_qkv, unsigned short* __restrict__ d_proj,
                           unsigned short* __restrict__ d_fc1, unsigned short* __restrict__ d_fc2,
                           unsigned short* __restrict__ d_la,  unsigned short* __restrict__ d_ad) {
    int stride = gridDim.x * 256;
    for (int i4 = blockIdx.x * 256 + threadIdx.x; i4 < 3227648; i4 += stride) {
        const float* s; unsigned short* d; int local;
        if (i4 < 786432)       { s = s_qkv;  d = d_qkv;  local = i4; }
        else if (i4 < 1048576) { s = s_proj; d = d_proj; local = i4 - 786432; }
        else if (i4 < 2097152) { s = s_fc1;  d = d_fc1;  local = i4 - 1048576; }
        else if (i4 < 3145728) { s = s_fc2;  d = d_fc2;  local = i4 - 2097152; }
        else if (i4 < 3162112) { s = s_la;   d = d_la;   local = i4 - 3145728; }
        else                   { s = s_ad;   d = d_ad;   local = i4 - 3162112; }
        float4 v = ((const float4*)s)[local];
        ushort4v o;
        o[0] = f2bf(v.x); o[1] = f2bf(v.y); o[2] = f2bf(v.z); o[3] = f2bf(v.w);
        ((ushort4v*)d)[local] = o;
    }
}
// lora_B [4][3072][16] -> Bcat[o][x*16+r]
__global__ void k_pack_bcat(const float* __restrict__ Bw, unsigned short* __restrict__ out) {
    int i = blockIdx.x * 256 + threadIdx.x;
    if (i >= 3072 * 64) return;
    int o = i >> 6, j = i & 63, x = j >> 4, r = j & 15;
    out[o * 64 + j] = f2bf(Bw[x * 3072 * 16 + o * 16 + r]);
}
// ad_up_w [4][1024][64] -> U[o][x*64+h]
__global__ void k_pack_u(const float* __restrict__ Uw, unsigned short* __restrict__ out) {
    int i = blockIdx.x * 256 + threadIdx.x;
    if (i >= 1024 * 256) return;
    int o = i >> 8, j = i & 255, x = j >> 6, h = j & 63;
    out[o * 256 + j] = f2bf(Uw[x * 65536 + o * 64 + h]);
}

// ---------- fused layernorm + 4-expert gate softmax (+ optional d_out prefill) ----------
template<bool FC2I>
__global__ __launch_bounds__(256) void k_ln_gates(const float* __restrict__ x,
                                                  const float* __restrict__ g,
                                                  const float* __restrict__ b,
                                                  const float* __restrict__ gw,
                                                  unsigned short* __restrict__ out,
                                                  float* __restrict__ gates,
                                                  const float* __restrict__ fc2b,
                                                  const float* __restrict__ upb,
                                                  float* __restrict__ out2) {
    int t = blockIdx.x;
    int tid = threadIdx.x;
    const float* xp = x + (size_t)t * EMB;
    float4 v = ((const float4*)xp)[tid];
    float s = v.x + v.y + v.z + v.w;
    float sq = v.x * v.x + v.y * v.y + v.z * v.z + v.w * v.w;
    #pragma unroll
    for (int off = 32; off > 0; off >>= 1) {
        s += __shfl_down(s, off);
        sq += __shfl_down(sq, off);
    }
    __shared__ float red[8];
    if ((tid & 63) == 0) { red[tid >> 6] = s; red[(tid >> 6) + 4] = sq; }
    __syncthreads();
    float S = red[0] + red[1] + red[2] + red[3];
    float SQ = red[4] + red[5] + red[6] + red[7];
    float mean = S * (1.0f / EMB);
    float var = SQ * (1.0f / EMB) - mean * mean;
    float rstd = rsqrtf(var + 1e-6f);
    float4 gv = ((const float4*)g)[tid];
    float4 bv = ((const float4*)b)[tid];
    float n0 = (v.x - mean) * rstd * gv.x + bv.x;
    float n1 = (v.y - mean) * rstd * gv.y + bv.y;
    float n2 = (v.z - mean) * rstd * gv.z + bv.z;
    float n3 = (v.w - mean) * rstd * gv.w + bv.w;
    ushort4v o;
    o[0] = f2bf(n0); o[1] = f2bf(n1); o[2] = f2bf(n2); o[3] = f2bf(n3);
    ((ushort4v*)(out + (size_t)t * EMB))[tid] = o;
    float p[4];
    #pragma unroll
    for (int xx = 0; xx < 4; ++xx) {
        float4 gr = ((const float4*)(gw + xx * EMB))[tid];
        p[xx] = n0 * gr.x + n1 * gr.y + n2 * gr.z + n3 * gr.w;
    }
    #pragma unroll
    for (int off = 32; off > 0; off >>= 1) {
        #pragma unroll
        for (int xx = 0; xx < 4; ++xx) p[xx] += __shfl_down(p[xx], off);
    }
    __shared__ float red2[4][4];
    __shared__ float agb[4];
    if ((tid & 63) == 0) {
        #pragma unroll
        for (int xx = 0; xx < 4; ++xx) red2[tid >> 6][xx] = p[xx];
    }
    __syncthreads();
    if (tid == 0) {
        float l[4];
        #pragma unroll
        for (int xx = 0; xx < 4; ++xx) l[xx] = red2[0][xx] + red2[1][xx] + red2[2][xx] + red2[3][xx];
        float m = fmaxf(fmaxf(l[0], l[1]), fmaxf(l[2], l[3]));
        float e[4], ssum = 0.f;
        #pragma unroll
        for (int xx = 0; xx < 4; ++xx) { e[xx] = expf(l[xx] - m); ssum += e[xx]; }
        float inv = 1.0f / ssum;
        #pragma unroll
        for (int xx = 0; xx < 4; ++xx) {
            float gg = e[xx] * inv;
            gates[t * 4 + xx] = gg;
            if (FC2I) agb[xx] = gg;
        }
    }
    if (FC2I) {
        __syncthreads();
        float g0 = agb[0], g1 = agb[1], g2 = agb[2], g3 = agb[3];
        float4 b0 = ((const float4*)(upb + 0 * EMB))[tid];
        float4 b1 = ((const float4*)(upb + 1 * EMB))[tid];
        float4 b2 = ((const float4*)(upb + 2 * EMB))[tid];
        float4 b3 = ((const float4*)(upb + 3 * EMB))[tid];
        float4 fb = ((const float4*)fc2b)[tid];
        float4 r;
        r.x = v.x + fb.x + g0 * b0.x + g1 * b1.x + g2 * b2.x + g3 * b3.x;
        r.y = v.y + fb.y + g0 * b0.y + g1 * b1.y + g2 * b2.y + g3 * b3.y;
        r.z = v.z + fb.z + g0 * b0.z + g1 * b1.z + g2 * b2.z + g3 * b3.z;
        r.w = v.w + fb.w + g0 * b0.w + g1 * b1.w + g2 * b2.w + g3 * b3.w;
        ((float4*)(out2 + (size_t)t * EMB))[tid] = r;
    }
}

// ---------- MFMA GEMM (R15/R17 structure; hazards proven R11; swizzle 0-conflict R12) ----------
#define BAR __builtin_amdgcn_s_barrier()

template<bool GELU, bool BF16OUT, int GG, int MF, int NF, int CN>
__global__ __launch_bounds__(256) void k_gemm(
    const unsigned short* __restrict__ A, int lda,
    const unsigned short* __restrict__ W, int ldw, int K1,
    int M, int N,
    const unsigned short* __restrict__ A2, const unsigned short* __restrict__ W2, int K2,
    const float* __restrict__ bias, const float* __restrict__ resid,
    const float* __restrict__ aux,
    void* __restrict__ Cout, int ldc, int gy)
{
    constexpr int CA = MF * 4;            // A chunks (8 rows x 64 cols = 1KB each)
    constexpr int CB = NF * 4;            // B chunks
    constexpr int CT = CA + CB;
    constexpr int CPW = CT / 4;           // chunks staged per wave
    constexpr int BUFB = CT * 1024;
    __shared__ __attribute__((aligned(16))) char Sbuf[2 * BUFB];

    int tid = threadIdx.x;
    int nwg = gridDim.x, orig = blockIdx.x;
    int xcd = orig & 7, lid = orig >> 3;
    int q = nwg >> 3, r = nwg & 7;
    int wg = (xcd < r ? xcd * (q + 1) : r * (q + 1) + (xcd - r) * q) + lid;
    // chunked decode: (nc, mt, ni)
    int nmt = nwg / gy;
    int ni = wg % CN;
    int tmp = wg / CN;
    int mt = tmp % nmt;
    int nt = (tmp / nmt) * CN + ni;
    int bm = mt * (MF * 32);
    int bn = nt * (NF * 32);

    int l = tid & 63, w = tid >> 6;
    int wr = w >> 1, wc = w & 1;
    int lr = l & 15;
    int sslot = (((l & 7) ^ (l >> 3)) << 3);   // inverse-swizzled source slot (elems)

    int KT1 = K1 >> 6, KT2 = K2 >> 6;
    int KT = KT1 + KT2;

    const unsigned short* A2s = A2 ? A2 : A;
    const unsigned short* W2s = W2 ? W2 : W;
    int K2s = A2 ? K2 : lda;

    // per-thread staging sources (rows clamped: garbage feeds only dead rows/cols)
    const unsigned short* sp1[CPW];
    const unsigned short* sp2[CPW];
    int ldsu[CPW];                        // wave-uniform LDS chunk base offsets
    #pragma unroll
    for (int j = 0; j < CPW; ++j) {
        int c = w * CPW + j;
        ldsu[j] = c << 10;
        if (c < CA) {
            int rw = bm + c * 8 + (l >> 3); if (rw > M - 1) rw = M - 1;
            sp1[j] = A + (size_t)rw * lda + sslot;
            sp2[j] = A2s + (size_t)rw * K2s + sslot;
        } else {
            int rw = bn + (c - CA) * 8 + (l >> 3); if (rw > N - 1) rw = N - 1;
            sp1[j] = W + (size_t)rw * ldw + sslot;
            sp2[j] = W2s + (size_t)rw * K2s + sslot;
        }
    }

    // swizzled, loop-invariant ds_read byte offsets
    int offA[MF][2], offB[NF][2];
    #pragma unroll
    for (int m = 0; m < MF; ++m)
        #pragma unroll
        for (int ks = 0; ks < 2; ++ks) {
            int rw = wr * (MF * 16) + m * 16 + lr;
            int g = ks * 4 + (l >> 4);
            offA[m][ks] = (rw << 7) + ((g ^ (rw & 7)) << 4);
        }
    #pragma unroll
    for (int n = 0; n < NF; ++n)
        #pragma unroll
        for (int ks = 0; ks < 2; ++ks) {
            int rw = wc * (NF * 16) + n * 16 + lr;
            int g = ks * 4 + (l >> 4);
            offB[n][ks] = (CA << 10) + (rw << 7) + ((g ^ (rw & 7)) << 4);
        }

    f32x4 acc[MF][NF];
    #pragma unroll
    for (int m = 0; m < MF; ++m)
        #pragma unroll
        for (int n = 0; n < NF; ++n) acc[m][n] = (f32x4){0.f, 0.f, 0.f, 0.f};

    auto stage = [&](int ss, int bb) {
        char* db = Sbuf + bb * BUFB;
        if (ss < KT1) {
            int ko = ss << 6;
            #pragma unroll
            for (int j = 0; j < CPW; ++j) async16(db + ldsu[j], sp1[j] + ko);
        } else {
            int ko = (ss - KT1) << 6;
            #pragma unroll
            for (int j = 0; j < CPW; ++j) async16(db + ldsu[j], sp2[j] + ko);
        }
    };

    stage(0, 0);

    #pragma unroll 1
    for (int t = 0; t < KT; ++t) {
        asm volatile("s_waitcnt vmcnt(0)" ::: "memory");  // my stage(t) landed
        BAR;                                // all waves' stage(t) landed; t-1 reads consumed
        __builtin_amdgcn_sched_barrier(0);  // pin reads below the barrier
        int s = t + 1; if (s >= KT) s = 0;  // wrap re-stage: buffer never read after
        stage(s, (t + 1) & 1);              // WAR safe post-barrier (buf read at t-1)
        const char* base = Sbuf + (t & 1) * BUFB;
        bf16x8 af[MF][2], bfr[NF][2];
        #pragma unroll
        for (int m = 0; m < MF; ++m)
            #pragma unroll
            for (int ks = 0; ks < 2; ++ks) af[m][ks] = *(const bf16x8*)(base + offA[m][ks]);
        #pragma unroll
        for (int n = 0; n < NF; ++n)
            #pragma unroll
            for (int ks = 0; ks < 2; ++ks) bfr[n][ks] = *(const bf16x8*)(base + offB[n][ks]);
        __builtin_amdgcn_s_setprio(1);
        #pragma unroll
        for (int m = 0; m < MF; ++m)
            #pragma unroll
            for (int n = 0; n < NF; ++n)
                #pragma unroll
                for (int ks = 0; ks < 2; ++ks)
                    acc[m][n] = __builtin_amdgcn_mfma_f32_16x16x32_bf16(af[m][ks], bfr[n][ks], acc[m][n], 0, 0, 0);
        __builtin_amdgcn_s_setprio(0);
    }

    int rbase = bm + wr * (MF * 16);
    int cbase = bn + wc * (NF * 16);
    #pragma unroll
    for (int n = 0; n < NF; ++n) {
        int col = cbase + n * 16 + lr;
        if (col >= N) continue;
        float bv = bias ? bias[col] : 0.0f;
        #pragma unroll
        for (int m = 0; m < MF; ++m) {
            #pragma unroll
            for (int rr = 0; rr < 4; ++rr) {
                int row = rbase + m * 16 + (l >> 4) * 4 + rr;
                if (row >= M) continue;
                float c = acc[m][n][rr] + bv;
                if (GELU) c = gelu_exact(c);
                if (GG > 0) c *= aux[row * 4 + col / (GG > 0 ? GG : 1)];
                if (resid) c += resid[(size_t)row * ldc + col];
                if (BF16OUT) ((unsigned short*)Cout)[(size_t)row * ldc + col] = f2bf(c);
                else ((float*)Cout)[(size_t)row * ldc + col] = c;
            }
        }
    }
}

// ---------- flash attention: one block per (b*h, 64-row q tile) ----------
__global__ __launch_bounds__(256) void k_attn(const unsigned short* __restrict__ qkv,
                                              unsigned short* __restrict__ ctx) {
    int bh = blockIdx.x;
    int qt = blockIdx.y;
    int b = bh >> 4, h = bh & 15;
    int tid = threadIdx.x;
    int l = tid & 63;
    int w = tid >> 6;
    int lr = l & 15;
    int lk = (l >> 4) * 8;

    __shared__ unsigned short Qs[64][72];
    __shared__ unsigned short Ks[64][72];
    __shared__ unsigned short Vt[64][72];
    __shared__ unsigned short Ps[64][72];

    const size_t base = (size_t)b * NSEQ * NQKV + (size_t)h * 64;
    int q0 = qt * 64;

    {   // vector Q staging; 1/8 scale folded into S post-MFMA
        int row = tid >> 2, ds = (tid & 3) * 16;
        int qrow = q0 + row;
        if (qrow < NSEQ) {
            const unsigned short* src = qkv + base + (size_t)qrow * NQKV + ds;
            *(ushort8*)&Qs[row][ds] = *(const ushort8*)src;
            *(ushort8*)&Qs[row][ds + 8] = *(const ushort8*)(src + 8);
        } else {
            ushort8 z = {};
            *(ushort8*)&Qs[row][ds] = z;
            *(ushort8*)&Qs[row][ds + 8] = z;
        }
    }

    float m_run[4], l_run[4];
    f32x4 o[4];
    #pragma unroll
    for (int r = 0; r < 4; ++r) { m_run[r] = -1e30f; l_run[r] = 0.0f; }
    #pragma unroll
    for (int n = 0; n < 4; ++n) o[n] = (f32x4){0.f, 0.f, 0.f, 0.f};

    for (int kt = 0; kt < 10; ++kt) {
        __syncthreads();
        {
            int row = tid >> 2, ds = (tid & 3) * 16;
            int key = kt * 64 + row;
            if (key < NSEQ) {
                const unsigned short* ksrc = qkv + base + (size_t)key * NQKV + 1024 + ds;
                *(ushort8*)&Ks[row][ds] = *(const ushort8*)ksrc;
                *(ushort8*)&Ks[row][ds + 8] = *(const ushort8*)(ksrc + 8);
                const unsigned short* vsrc = qkv + base + (size_t)key * NQKV + 2048 + ds;
                #pragma unroll
                for (int j = 0; j < 16; ++j) Vt[ds + j][row] = vsrc[j];
            } else {
                ushort8 z = {};
                *(ushort8*)&Ks[row][ds] = z;
                *(ushort8*)&Ks[row][ds + 8] = z;
                #pragma unroll
                for (int j = 0; j < 16; ++j) Vt[ds + j][row] = 0;
            }
        }
        __syncthreads();

        f32x4 s[4];
        #pragma unroll
        for (int n = 0; n < 4; ++n) s[n] = (f32x4){0.f, 0.f, 0.f, 0.f};
        #pragma unroll
        for (int ks = 0; ks < 2; ++ks) {
            bf16x8 qa = *(const bf16x8*)&Qs[w * 16 + lr][ks * 32 + lk];
            #pragma unroll
            for (int n = 0; n < 4; ++n) {
                bf16x8 kb = *(const bf16x8*)&Ks[n * 16 + lr][ks * 32 + lk];
                s[n] = __builtin_amdgcn_mfma_f32_16x16x32_bf16(qa, kb, s[n], 0, 0, 0);
            }
        }
        #pragma unroll
        for (int n = 0; n < 4; ++n) {
            #pragma unroll
            for (int r = 0; r < 4; ++r) s[n][r] *= 0.125f;
        }
        #pragma unroll
        for (int n = 0; n < 4; ++n) {
            int col = kt * 64 + n * 16 + lr;
            if (col >= NSEQ) {
                #pragma unroll
                for (int r = 0; r < 4; ++r) s[n][r] = -1e30f;
            }
        }
        float tmax[4];
        #pragma unroll
        for (int r = 0; r < 4; ++r)
            tmax[r] = fmaxf(fmaxf(s[0][r], s[1][r]), fmaxf(s[2][r], s[3][r]));
        #pragma unroll
        for (int off = 1; off < 16; off <<= 1) {
            #pragma unroll
            for (int r = 0; r < 4; ++r) tmax[r] = fmaxf(tmax[r], __shfl_xor(tmax[r], off));
        }
        float alpha[4], rs[4];
        #pragma unroll
        for (int r = 0; r < 4; ++r) {
            float mn = fmaxf(m_run[r], tmax[r]);
            alpha[r] = __expf(m_run[r] - mn);
            m_run[r] = mn;
            rs[r] = 0.0f;
        }
        #pragma unroll
        for (int n = 0; n < 4; ++n) {
            #pragma unroll
            for (int r = 0; r < 4; ++r) {
                float p = __expf(s[n][r] - m_run[r]);
                s[n][r] = p;
                rs[r] += p;
            }
        }
        #pragma unroll
        for (int off = 1; off < 16; off <<= 1) {
            #pragma unroll
            for (int r = 0; r < 4; ++r) rs[r] += __shfl_xor(rs[r], off);
        }
        #pragma unroll
        for (int r = 0; r < 4; ++r) l_run[r] = l_run[r] * alpha[r] + rs[r];
        #pragma unroll
        for (int n = 0; n < 4; ++n) {
            #pragma unroll
            for (int r = 0; r < 4; ++r) o[n][r] *= alpha[r];
        }
        #pragma unroll
        for (int n = 0; n < 4; ++n) {
            #pragma unroll
            for (int r = 0; r < 4; ++r)
                Ps[w * 16 + (l >> 4) * 4 + r][n * 16 + lr] = f2bf(s[n][r]);
        }
        __syncthreads();
        #pragma unroll
        for (int ks = 0; ks < 2; ++ks) {
            bf16x8 pa = *(const bf16x8*)&Ps[w * 16 + lr][ks * 32 + lk];
            #pragma unroll
            for (int n = 0; n < 4; ++n) {
                bf16x8 vb = *(const bf16x8*)&Vt[n * 16 + lr][ks * 32 + lk];
                o[n] = __builtin_amdgcn_mfma_f32_16x16x32_bf16(pa, vb, o[n], 0, 0, 0);
            }
        }
    }
    #pragma unroll
    for (int r = 0; r < 4; ++r) {
        int qrow = q0 + w * 16 + (l >> 4) * 4 + r;
        if (qrow < NSEQ) {
            float inv = (l_run[r] > 0.f) ? 1.0f / l_run[r] : 0.0f;
            #pragma unroll
            for (int n = 0; n < 4; ++n)
                ctx[((size_t)b * NSEQ + qrow) * EMB + h * 64 + n * 16 + lr] = f2bf(o[n][r] * inv);
        }
    }
}

extern "C" void kernel_launch(void* const* d_in, const int* in_sizes, int n_in,
                              void* d_out, int out_size, void* d_ws, size_t ws_size,
                              hipStream_t stream) {
    const float* tokens      = (const float*)d_in[0];
    const float* ln1_g       = (const float*)d_in[1];
    const float* ln1_b       = (const float*)d_in[2];
    const float* qkv_w       = (const float*)d_in[3];
    const float* qkv_b       = (const float*)d_in[4];
    const float* proj_w      = (const float*)d_in[5];
    const float* proj_b      = (const float*)d_in[6];
    const float* lora_gate_w = (const float*)d_in[7];
    const float* lora_A      = (const float*)d_in[8];
    const float* lora_B      = (const float*)d_in[9];
    const float* ln2_g       = (const float*)d_in[10];
    const float* ln2_b       = (const float*)d_in[11];
    const float* fc1_w       = (const float*)d_in[12];
    const float* fc1_b       = (const float*)d_in[13];
    const float* fc2_w       = (const float*)d_in[14];
    const float* fc2_b       = (const float*)d_in[15];
    const float* ad_gate_w   = (const float*)d_in[16];
    const float* ad_down_w   = (const float*)d_in[17];
    const float* ad_down_b   = (const float*)d_in[18];
    const float* ad_up_w     = (const float*)d_in[19];
    const float* ad_up_b     = (const float*)d_in[20];

    char* ws = (char*)d_ws;
    size_t off = 0;
    auto alloc = [&](size_t bytes) -> void* {
        void* p = ws + off;
        off += (bytes + 255) & ~(size_t)255;
        return p;
    };

    unsigned short* w_qkv  = (unsigned short*)alloc((size_t)NQKV * EMB * 2);
    unsigned short* w_proj = (unsigned short*)alloc((size_t)EMB * EMB * 2);
    unsigned short* w_fc1  = (unsigned short*)alloc((size_t)FFD * EMB * 2);
    unsigned short* w_fc2  = (unsigned short*)alloc((size_t)EMB * FFD * 2);
    unsigned short* w_acat = (unsigned short*)alloc((size_t)64 * EMB * 2);
    unsigned short* w_bcat = (unsigned short*)alloc((size_t)NQKV * 64 * 2);
    unsigned short* w_dcat = (unsigned short*)alloc((size_t)256 * EMB * 2);
    unsigned short* w_u    = (unsigned short*)alloc((size_t)EMB * 256 * 2);

    unsigned short* u1 = (unsigned short*)alloc((size_t)TOK * EMB * 2);  // normed -> mlpin
    unsigned short* u2 = (unsigned short*)alloc((size_t)TOK * EMB * 2);  // ctx
    unsigned short* u3 = (unsigned short*)alloc((size_t)TOK * FFD * 2);  // qkv -> h1
    float* tok2  = (float*)alloc((size_t)TOK * EMB * 4);
    unsigned short* hw  = (unsigned short*)alloc((size_t)TOK * 64 * 2);
    unsigned short* ahw = (unsigned short*)alloc((size_t)TOK * 256 * 2);
    float* gates = (float*)alloc((size_t)TOK * 4 * 4);
    float* ag    = (float*)alloc((size_t)TOK * 4 * 4);

    unsigned short* normed = u1;
    unsigned short* mlpin  = u1;
    unsigned short* ctx    = u2;
    unsigned short* qkv    = u3;
    unsigned short* h1     = u3;

    // ---- weight conversion / packing (3 dispatches) ----
    k_pack_all<<<2048, 256, 0, stream>>>(qkv_w, proj_w, fc1_w, fc2_w, lora_A, ad_down_w,
                                         w_qkv, w_proj, w_fc1, w_fc2, w_acat, w_dcat);
    k_pack_bcat<<<(NQKV * 64 + 255) / 256, 256, 0, stream>>>(lora_B, w_bcat);
    k_pack_u<<<(EMB * 256 + 255) / 256, 256, 0, stream>>>(ad_up_w, w_u);

    // ---- forward ----
    k_ln_gates<false><<<TOK, 256, 0, stream>>>(tokens, ln1_g, ln1_b, lora_gate_w,
                                               normed, gates, nullptr, nullptr, nullptr);
    // lora down: hw = gates * (normed @ lora_A^T), 64x64 tiles
    k_gemm<false, true, 16, 2, 2, 1><<<145, 256, 0, stream>>>(
        normed, EMB, w_acat, EMB, EMB, TOK, 64,
        nullptr, nullptr, 0, nullptr, nullptr, gates, hw, 64, 1);
    // qkv = normed @ qkv_w^T + hw @ bcat^T + qkv_b  (128x64, gy=48, cn=8)
    k_gemm<false, true, 0, 4, 2, 8><<<73 * 48, 256, 0, stream>>>(
        normed, EMB, w_qkv, EMB, EMB, TOK, NQKV,
        hw, w_bcat, 64, qkv_b, nullptr, nullptr, qkv, NQKV, 48);
    k_attn<<<dim3(256, 10), 256, 0, stream>>>(qkv, ctx);
    // tok2 = tokens + ctx @ proj^T + proj_b   (fp32, 128x64, gy=16, cn=8)
    k_gemm<false, false, 0, 4, 2, 8><<<73 * 16, 256, 0, stream>>>(
        ctx, EMB, w_proj, EMB, EMB, TOK, EMB,
        nullptr, nullptr, 0, proj_b, tokens, nullptr, tok2, EMB, 16);
    // LN2 + adapter gates + d_out prefill (tok2 + fc2_b + ag@ad_up_b) in one pass
    k_ln_gates<true><<<TOK, 256, 0, stream>>>(tok2, ln2_g, ln2_b, ad_gate_w,
                                              mlpin, ag, fc2_b, ad_up_b, (float*)d_out);
    // adapter down: ahw = ag * gelu(mlpin @ d^T + db)  (64x64, gy=4, cn=4)
    k_gemm<true, true, 64, 2, 2, 4><<<145 * 4, 256, 0, stream>>>(
        mlpin, EMB, w_dcat, EMB, EMB, TOK, 256,
        nullptr, nullptr, 0, ad_down_b, nullptr, ag, ahw, 256, 4);
    // h1 = gelu(mlpin @ fc1^T + fc1_b)  (128x64, gy=64, cn=8)
    k_gemm<true, true, 0, 4, 2, 8><<<73 * 64, 256, 0, stream>>>(
        mlpin, EMB, w_fc1, EMB, EMB, TOK, FFD,
        nullptr, nullptr, 0, fc1_b, nullptr, nullptr, h1, FFD, 64);
    // d_out = prefill + h1 @ fc2^T + ahw @ u^T  (128x64, gy=16, cn=8; resid aliases Cout,
    // each elem read-then-written by the same thread)
    k_gemm<false, false, 0, 4, 2, 8><<<73 * 16, 256, 0, stream>>>(
        h1, FFD, w_fc2, FFD, FFD, TOK, EMB,
        ahw, w_u, 256, nullptr, (const float*)d_out, nullptr, (float*)d_out, EMB, 16);
}